// Round 1
// baseline (551.664 us; speedup 1.0000x reference)
//
#include <hip/hip_runtime.h>
#include <hip/hip_bf16.h>
#include <cstdint>

// CAM (DANet channel attention): out = gamma * softmax(rowmax(E)-E) @ q + x,
// E = q q^T per batch, q = x reshaped [B, C, N], B=16 C=512 N=4096.
//
// Precision: energy feeds an exp(); pure bf16 gives ~0.2-0.9 abs energy error
// (too big). Split x = hi + lo (both bf16), E = HH^T + HL^T + LH^T in fp32
// MFMA accumulators -> ~1e-3 energy error. PV + weights in plain bf16 (safe).

typedef short    bf16x8 __attribute__((ext_vector_type(8)));
typedef float    f32x4  __attribute__((ext_vector_type(4)));
typedef uint16_t u16x4  __attribute__((ext_vector_type(4)));
typedef uint16_t u16x8  __attribute__((ext_vector_type(8)));

#define AS1 __attribute__((address_space(1)))
#define AS3 __attribute__((address_space(3)))

__device__ __forceinline__ void load_lds16(const void* g, void* l) {
  // async global->LDS, 16B/lane; LDS dest = wave-uniform base + lane*16
  __builtin_amdgcn_global_load_lds((const AS1 unsigned int*)g,
                                   (AS3 unsigned int*)l, 16, 0, 0);
}

static constexpr int  BB  = 16, C = 512, N = 4096;
static constexpr long XSZ = (long)BB * C * N;   // 33,554,432 elems
static constexpr long ESZ = (long)BB * C * C;   //  4,194,304 elems

// ---------------- 1. split fp32 -> bf16 hi/lo + transpose hi ----------------
__global__ __launch_bounds__(256) void cam_split(
    const float* __restrict__ x, uint16_t* __restrict__ qhi,
    uint16_t* __restrict__ qlo, uint16_t* __restrict__ qT) {
  __shared__ uint16_t tile[64][65];  // +1 pad breaks transpose-read conflicts
  const int t  = threadIdx.x;
  const int b  = blockIdx.z;
  const int c0 = blockIdx.y * 64;
  const int n0 = blockIdx.x * 64;
  const float*    xb   = x   + (long)b * C * N;
  uint16_t*       qhib = qhi + (long)b * C * N;
  uint16_t*       qlob = qlo + (long)b * C * N;
  uint16_t*       qTb  = qT  + (long)b * N * C;
  const int cl = t >> 4;          // 0..15
  const int nl = (t & 15) * 4;    // 0..60
  for (int r = 0; r < 4; ++r) {
    const int  c   = cl + r * 16;
    const long off = (long)(c0 + c) * N + n0 + nl;
    const float4 v = *(const float4*)(xb + off);
    float vv[4] = {v.x, v.y, v.z, v.w};
    u16x4 hv, lv;
    for (int k = 0; k < 4; ++k) {
      __hip_bfloat16 hb = __float2bfloat16(vv[k]);
      float hf = __bfloat162float(hb);
      __hip_bfloat16 lb = __float2bfloat16(vv[k] - hf);
      hv[k] = *(uint16_t*)&hb;
      lv[k] = *(uint16_t*)&lb;
      tile[c][nl + k] = hv[k];
    }
    *(u16x4*)(qhib + off) = hv;
    *(u16x4*)(qlob + off) = lv;
  }
  __syncthreads();
  for (int r = 0; r < 4; ++r) {
    const int n  = cl + r * 16;
    const int cc = (t & 15) * 4;
    u16x4 o = {tile[cc + 0][n], tile[cc + 1][n], tile[cc + 2][n], tile[cc + 3][n]};
    *(u16x4*)(qTb + (long)(n0 + n) * C + c0 + cc) = o;
  }
}

// ---------------- 2. energy = HH^T + HL^T + LH^T (split-K=2) ----------------
__global__ __launch_bounds__(256) void cam_energy(
    const uint16_t* __restrict__ qhi, const uint16_t* __restrict__ qlo,
    float* __restrict__ E) {
  __shared__ uint16_t smem[4 * 128 * 32];  // Ahi | Alo | Bhi | Blo, 32 KB
  const int t = threadIdx.x;
  const int wave = t >> 6, lane = t & 63;
  const int b  = blockIdx.y;
  const int ti = blockIdx.x & 3, tj = blockIdx.x >> 2;
  const int z  = blockIdx.z;                 // K-split index
  const long base = (long)b * C * N;
  const int i0 = ti * 128, j0 = tj * 128;
  const int lrow = lane >> 2;                // staging: 4 lanes/row
  const int lk8  = (lane & 3) * 8;
  const int wr = wave >> 1, wc = wave & 1;   // 64x64 quadrant per wave
  const int m16 = lane & 15, q4 = lane >> 4; // MFMA fragment mapping
  f32x4 acc[4][4] = {};
  const int k0 = z * 2048, k1 = k0 + 2048;
  for (int kk = k0; kk < k1; kk += 32) {
    for (int s = 0; s < 2; ++s) {
      const int row = (s * 4 + wave) * 16 + lrow;
      const uint32_t loff = (uint32_t)(s * 4 + wave) * 1024;  // wave-uniform
      const long ga = base + (long)(i0 + row) * N + kk + lk8;
      const long gb = base + (long)(j0 + row) * N + kk + lk8;
      char* lp = (char*)smem + loff;
      load_lds16(qhi + ga, lp);
      load_lds16(qlo + ga, lp + 8192);
      load_lds16(qhi + gb, lp + 16384);
      load_lds16(qlo + gb, lp + 24576);
    }
    __syncthreads();
    bf16x8 ah[4], al[4], bh[4], bl[4];
    for (int i = 0; i < 4; ++i) {
      const int r = wr * 64 + i * 16 + m16;
      ah[i] = *(const bf16x8*)(smem +         r * 32 + q4 * 8);
      al[i] = *(const bf16x8*)(smem +  4096 + r * 32 + q4 * 8);
    }
    for (int j = 0; j < 4; ++j) {
      const int r = wc * 64 + j * 16 + m16;
      bh[j] = *(const bf16x8*)(smem +  8192 + r * 32 + q4 * 8);
      bl[j] = *(const bf16x8*)(smem + 12288 + r * 32 + q4 * 8);
    }
    for (int i = 0; i < 4; ++i)
      for (int j = 0; j < 4; ++j) {
        acc[i][j] = __builtin_amdgcn_mfma_f32_16x16x32_bf16(ah[i], bh[j], acc[i][j], 0, 0, 0);
        acc[i][j] = __builtin_amdgcn_mfma_f32_16x16x32_bf16(ah[i], bl[j], acc[i][j], 0, 0, 0);
        acc[i][j] = __builtin_amdgcn_mfma_f32_16x16x32_bf16(al[i], bh[j], acc[i][j], 0, 0, 0);
      }
    __syncthreads();
  }
  float* Eb = E + (long)z * ESZ + (long)b * C * C;
  for (int i = 0; i < 4; ++i) {
    const int rb = i0 + wr * 64 + i * 16 + q4 * 4;  // C/D: row=(lane>>4)*4+reg
    for (int j = 0; j < 4; ++j) {
      const int cc = j0 + wc * 64 + j * 16 + m16;   // C/D: col=lane&15
      for (int r = 0; r < 4; ++r)
        Eb[(long)(rb + r) * C + cc] = acc[i][j][r];
    }
  }
}

// ---------------- 3. softmax(max-E) == exp(rowmin-E)/sum, -> bf16 ----------
__global__ __launch_bounds__(256) void cam_softmax(
    const float* __restrict__ E, uint16_t* __restrict__ attn) {
  const int t = threadIdx.x;
  const int wave = t >> 6, lane = t & 63;
  const long row = (long)blockIdx.x * 4 + wave;   // 0..8191
  const float* e0 = E + row * C + lane * 8;
  const float* e1 = e0 + ESZ;                     // second K-split partial
  float vv[8];
  {
    const float4 a0 = *(const float4*)e0;
    const float4 a1 = *(const float4*)(e0 + 4);
    const float4 b0 = *(const float4*)e1;
    const float4 b1 = *(const float4*)(e1 + 4);
    vv[0] = a0.x + b0.x; vv[1] = a0.y + b0.y; vv[2] = a0.z + b0.z; vv[3] = a0.w + b0.w;
    vv[4] = a1.x + b1.x; vv[5] = a1.y + b1.y; vv[6] = a1.z + b1.z; vv[7] = a1.w + b1.w;
  }
  float m = vv[0];
  for (int k = 1; k < 8; ++k) m = fminf(m, vv[k]);
  for (int s = 32; s; s >>= 1) m = fminf(m, __shfl_xor(m, s));
  float w[8], sum = 0.f;
  for (int k = 0; k < 8; ++k) { w[k] = __expf(m - vv[k]); sum += w[k]; }
  for (int s = 32; s; s >>= 1) sum += __shfl_xor(sum, s);
  const float inv = 1.0f / sum;
  u16x8 o;
  for (int k = 0; k < 8; ++k) {
    __hip_bfloat16 h = __float2bfloat16(w[k] * inv);
    o[k] = *(uint16_t*)&h;
  }
  *(u16x8*)(attn + row * C + lane * 8) = o;
}

// ---------------- 4. out = gamma * (attn @ q) + x ---------------------------
__global__ __launch_bounds__(256) void cam_pv(
    const uint16_t* __restrict__ attn, const uint16_t* __restrict__ qT,
    const float* __restrict__ x, const float* __restrict__ gamma,
    float* __restrict__ out) {
  __shared__ uint16_t smem[2 * 128 * 32];  // A-tile | B-tile, 16 KB
  const int t = threadIdx.x;
  const int wave = t >> 6, lane = t & 63;
  const int b  = blockIdx.z;
  const int i0 = blockIdx.y * 128;  // channel-row tile
  const int n0 = blockIdx.x * 128;  // spatial-col tile
  const uint16_t* Ab = attn + (long)b * C * C;
  const uint16_t* Tb = qT   + (long)b * N * C;
  const int lrow = lane >> 2, lk8 = (lane & 3) * 8;
  const int wr = wave >> 1, wc = wave & 1;
  const int m16 = lane & 15, q4 = lane >> 4;
  f32x4 acc[4][4] = {};
  for (int kk = 0; kk < C; kk += 32) {
    for (int s = 0; s < 2; ++s) {
      const int row = (s * 4 + wave) * 16 + lrow;
      const uint32_t loff = (uint32_t)(s * 4 + wave) * 1024;
      char* lp = (char*)smem + loff;
      load_lds16(Ab + (long)(i0 + row) * C + kk + lk8, lp);
      load_lds16(Tb + (long)(n0 + row) * C + kk + lk8, lp + 8192);
    }
    __syncthreads();
    bf16x8 a[4], bb[4];
    for (int i = 0; i < 4; ++i)
      a[i]  = *(const bf16x8*)(smem +        (wr * 64 + i * 16 + m16) * 32 + q4 * 8);
    for (int j = 0; j < 4; ++j)
      bb[j] = *(const bf16x8*)(smem + 4096 + (wc * 64 + j * 16 + m16) * 32 + q4 * 8);
    for (int i = 0; i < 4; ++i)
      for (int j = 0; j < 4; ++j)
        acc[i][j] = __builtin_amdgcn_mfma_f32_16x16x32_bf16(a[i], bb[j], acc[i][j], 0, 0, 0);
    __syncthreads();
  }
  const float g = gamma[0];
  const float* xb = x   + (long)b * C * N;
  float*       ob = out + (long)b * C * N;
  for (int i = 0; i < 4; ++i) {
    const int rb = i0 + wr * 64 + i * 16 + q4 * 4;
    for (int j = 0; j < 4; ++j) {
      const int cc = n0 + wc * 64 + j * 16 + m16;
      for (int r = 0; r < 4; ++r) {
        const long idx = (long)(rb + r) * N + cc;
        ob[idx] = g * acc[i][j][r] + xb[idx];
      }
    }
  }
}

extern "C" void kernel_launch(void* const* d_in, const int* in_sizes, int n_in,
                              void* d_out, int out_size, void* d_ws, size_t ws_size,
                              hipStream_t stream) {
  const float* x     = (const float*)d_in[0];
  const float* gamma = (const float*)d_in[1];
  float* out = (float*)d_out;
  char*  ws  = (char*)d_ws;
  // workspace layout (bytes): qhi 64MB | qlo 64MB | qT 64MB | E 2x16MB = 224MB
  uint16_t* qhi = (uint16_t*)ws;
  uint16_t* qlo = (uint16_t*)(ws + XSZ * 2);
  uint16_t* qT  = (uint16_t*)(ws + XSZ * 4);
  float*    E   = (float*)  (ws + XSZ * 6);
  uint16_t* attn = qlo;  // alias: qlo is dead after cam_energy

  cam_split  <<<dim3(N / 64, C / 64, BB), 256, 0, stream>>>(x, qhi, qlo, qT);
  cam_energy <<<dim3(16, BB, 2),          256, 0, stream>>>(qhi, qlo, E);
  cam_softmax<<<dim3((BB * C) / 4),       256, 0, stream>>>(E, attn);
  cam_pv     <<<dim3(N / 128, C / 128, BB), 256, 0, stream>>>(attn, qT, x, gamma, out);
}

// Round 3
// 450.038 us; speedup vs baseline: 1.2258x; 1.2258x over previous
//
#include <hip/hip_runtime.h>
#include <hip/hip_bf16.h>
#include <cstdint>

// CAM (DANet channel attention): out = gamma * softmax(rowmax(E)-E) @ q + x,
// E = q q^T per batch, q = x reshaped [B, C, N], B=16 C=512 N=4096.
//
// R3: identical to R2 except the cam_energy grid is the correct 640 blocks
// (10 triangle tiles x 16 batches x 4 k-splits). R2 launched 256 -> most of
// E held the 0xAA poison.

typedef short    bf16x8 __attribute__((ext_vector_type(8)));
typedef float    f32x4  __attribute__((ext_vector_type(4)));
typedef uint16_t u16x4  __attribute__((ext_vector_type(4)));
typedef uint16_t u16x8  __attribute__((ext_vector_type(8)));

#define AS1 __attribute__((address_space(1)))
#define AS3 __attribute__((address_space(3)))

__device__ __forceinline__ void load_lds16(const void* g, void* l) {
  __builtin_amdgcn_global_load_lds((const AS1 unsigned int*)g,
                                   (AS3 unsigned int*)l, 16, 0, 0);
}

static constexpr int  BB  = 16, C = 512, N = 4096;
static constexpr long XSZ = (long)BB * C * N;   // 33,554,432 elems
static constexpr long ESZ = (long)BB * C * C;   //  4,194,304 elems
static constexpr int  ZSPLIT = 4;

// ---------------- 1. transpose hi(RNE) for PV: qT[b][n][c] ------------------
__global__ __launch_bounds__(256) void cam_splitT(
    const float* __restrict__ x, uint16_t* __restrict__ qT) {
  __shared__ uint16_t tile[64][65];
  const int t  = threadIdx.x;
  const int b  = blockIdx.z;
  const int c0 = blockIdx.y * 64;
  const int n0 = blockIdx.x * 64;
  const float* xb  = x  + (long)b * C * N;
  uint16_t*    qTb = qT + (long)b * N * C;
  const int cl = t >> 4;
  const int nl = (t & 15) * 4;
  for (int r = 0; r < 4; ++r) {
    const int  c   = cl + r * 16;
    const long off = (long)(c0 + c) * N + n0 + nl;
    const float4 v = *(const float4*)(xb + off);
    const float vv[4] = {v.x, v.y, v.z, v.w};
    for (int k = 0; k < 4; ++k) {
      __hip_bfloat16 hb = __float2bfloat16(vv[k]);  // RNE for PV precision
      tile[c][nl + k] = *(uint16_t*)&hb;
    }
  }
  __syncthreads();
  for (int r = 0; r < 4; ++r) {
    const int n  = cl + r * 16;
    const int cc = (t & 15) * 4;
    u16x4 o = {tile[cc + 0][n], tile[cc + 1][n], tile[cc + 2][n], tile[cc + 3][n]};
    *(u16x4*)(qTb + (long)(n0 + n) * C + c0 + cc) = o;
  }
}

// RTZ split of 4 fp32 into packed bf16 hi (2 u32) + compensation lo (2 u32).
__device__ __forceinline__ void split4(float4 v, uint2& h, uint2& l) {
  const uint32_t u0 = __float_as_uint(v.x), u1 = __float_as_uint(v.y);
  const uint32_t u2 = __float_as_uint(v.z), u3 = __float_as_uint(v.w);
  const float r0 = v.x - __uint_as_float(u0 & 0xffff0000u);
  const float r1 = v.y - __uint_as_float(u1 & 0xffff0000u);
  const float r2 = v.z - __uint_as_float(u2 & 0xffff0000u);
  const float r3 = v.w - __uint_as_float(u3 & 0xffff0000u);
  h.x = (u0 >> 16) | (u1 & 0xffff0000u);
  h.y = (u2 >> 16) | (u3 & 0xffff0000u);
  l.x = (__float_as_uint(r0) >> 16) | (__float_as_uint(r1) & 0xffff0000u);
  l.y = (__float_as_uint(r2) >> 16) | (__float_as_uint(r3) & 0xffff0000u);
}

// -------- 2. energy = HH^T + HL^T + LH^T, triangle tiles, split-K=4 --------
__global__ __launch_bounds__(256) void cam_energy(
    const float* __restrict__ x, float* __restrict__ E) {
  __shared__ uint16_t smem[4 * 128 * 32];  // Ahi | Alo | Bhi | Blo, 32 KB
  const int tid = threadIdx.x;
  const int wave = tid >> 6, lane = tid & 63;
  // XCD swizzle: blocks of one (b,z) group share blockIdx % 8.
  const int idx = blockIdx.x;              // 0..639
  const int low = idx & 7, chunk = idx >> 3;
  const int gh = chunk / 10, t = chunk - gh * 10;
  const int g  = gh * 8 + low;             // 0..63 group = (b, z)
  const int b  = g >> 2, z = g & 3;
  const int ti = (t < 4) ? 0 : (t < 7) ? 1 : (t < 9) ? 2 : 3;
  const int tj = t - ((ti * (9 - ti)) >> 1) + ti;
  const bool diag = (ti == tj);
  const int i0 = ti * 128, j0 = tj * 128;
  const float* xb = x + (long)b * C * N;
  const int sr = tid >> 3;                 // staging row 0..31 (per pass)
  const int sc = (tid & 7) * 4;            // staging k-offset
  const float* pA = xb + (long)(i0 + sr) * N + sc;
  const float* pB = xb + (long)(j0 + sr) * N + sc;
  uint16_t* smAh = smem;
  uint16_t* smAl = smem + 4096;
  uint16_t* smBh = diag ? smem        : smem + 8192;
  uint16_t* smBl = diag ? smem + 4096 : smem + 12288;
  const int wr = wave >> 1, wc = wave & 1;
  const int m16 = lane & 15, q4 = lane >> 4;
  f32x4 acc[4][4] = {};
  const int k0 = z * (N / ZSPLIT);
  for (int kk = k0; kk < k0 + N / ZSPLIT; kk += 32) {
    for (int p = 0; p < 4; ++p) {
      const int row = p * 32 + sr;
      float4 va = *(const float4*)(pA + kk + (long)p * 32 * N);
      uint2 h, l;
      split4(va, h, l);
      *(uint2*)(smAh + row * 32 + sc) = h;
      *(uint2*)(smAl + row * 32 + sc) = l;
      if (!diag) {
        float4 vb = *(const float4*)(pB + kk + (long)p * 32 * N);
        split4(vb, h, l);
        *(uint2*)(smem + 8192 + row * 32 + sc) = h;
        *(uint2*)(smem + 12288 + row * 32 + sc) = l;
      }
    }
    __syncthreads();
    bf16x8 ah[4], al[4], bh[4], bl[4];
    for (int i = 0; i < 4; ++i) {
      const int r = wr * 64 + i * 16 + m16;
      ah[i] = *(const bf16x8*)(smAh + r * 32 + q4 * 8);
      al[i] = *(const bf16x8*)(smAl + r * 32 + q4 * 8);
    }
    for (int j = 0; j < 4; ++j) {
      const int r = wc * 64 + j * 16 + m16;
      bh[j] = *(const bf16x8*)(smBh + r * 32 + q4 * 8);
      bl[j] = *(const bf16x8*)(smBl + r * 32 + q4 * 8);
    }
    for (int i = 0; i < 4; ++i)
      for (int j = 0; j < 4; ++j) {
        acc[i][j] = __builtin_amdgcn_mfma_f32_16x16x32_bf16(ah[i], bh[j], acc[i][j], 0, 0, 0);
        acc[i][j] = __builtin_amdgcn_mfma_f32_16x16x32_bf16(ah[i], bl[j], acc[i][j], 0, 0, 0);
        acc[i][j] = __builtin_amdgcn_mfma_f32_16x16x32_bf16(al[i], bh[j], acc[i][j], 0, 0, 0);
      }
    __syncthreads();
  }
  float* Eb = E + (long)z * ESZ + (long)b * C * C;
  for (int i = 0; i < 4; ++i) {
    const int rb = i0 + wr * 64 + i * 16 + q4 * 4;
    for (int j = 0; j < 4; ++j) {
      const int cc = j0 + wc * 64 + j * 16 + m16;
      for (int r = 0; r < 4; ++r)
        Eb[(long)(rb + r) * C + cc] = acc[i][j][r];
      if (!diag)  // mirror: E[cc][rb..rb+3] = acc[0..3], contiguous float4
        *(f32x4*)(Eb + (long)cc * C + rb) = acc[i][j];
    }
  }
}

// ---------------- 3. softmax(max-E) == exp(rowmin-E)/sum, -> bf16 ----------
__global__ __launch_bounds__(256) void cam_softmax(
    const float* __restrict__ E, uint16_t* __restrict__ attn) {
  const int t = threadIdx.x;
  const int wave = t >> 6, lane = t & 63;
  const long row = (long)blockIdx.x * 4 + wave;   // 0..8191
  const float* e = E + row * C + lane * 8;
  float vv[8] = {};
  for (int z = 0; z < ZSPLIT; ++z) {
    const float4 a0 = *(const float4*)(e + (long)z * ESZ);
    const float4 a1 = *(const float4*)(e + (long)z * ESZ + 4);
    vv[0] += a0.x; vv[1] += a0.y; vv[2] += a0.z; vv[3] += a0.w;
    vv[4] += a1.x; vv[5] += a1.y; vv[6] += a1.z; vv[7] += a1.w;
  }
  float m = vv[0];
  for (int k = 1; k < 8; ++k) m = fminf(m, vv[k]);
  for (int s = 32; s; s >>= 1) m = fminf(m, __shfl_xor(m, s));
  float w[8], sum = 0.f;
  for (int k = 0; k < 8; ++k) { w[k] = __expf(m - vv[k]); sum += w[k]; }
  for (int s = 32; s; s >>= 1) sum += __shfl_xor(sum, s);
  const float inv = 1.0f / sum;
  u16x8 o;
  for (int k = 0; k < 8; ++k) {
    __hip_bfloat16 h = __float2bfloat16(w[k] * inv);
    o[k] = *(uint16_t*)&h;
  }
  *(u16x8*)(attn + row * C + lane * 8) = o;
}

// ---------------- 4. out = gamma * (attn @ q) + x ---------------------------
__global__ __launch_bounds__(256) void cam_pv(
    const uint16_t* __restrict__ attn, const uint16_t* __restrict__ qT,
    const float* __restrict__ x, const float* __restrict__ gamma,
    float* __restrict__ out) {
  __shared__ uint16_t smem[2 * 128 * 32];  // A-tile | B-tile, 16 KB
  const int t = threadIdx.x;
  const int wave = t >> 6, lane = t & 63;
  const int b  = blockIdx.z;
  const int i0 = blockIdx.y * 128;
  const int n0 = blockIdx.x * 128;
  const uint16_t* Ab = attn + (long)b * C * C;
  const uint16_t* Tb = qT   + (long)b * N * C;
  const int lrow = lane >> 2, lk8 = (lane & 3) * 8;
  const int wr = wave >> 1, wc = wave & 1;
  const int m16 = lane & 15, q4 = lane >> 4;
  f32x4 acc[4][4] = {};
  for (int kk = 0; kk < C; kk += 32) {
    for (int s = 0; s < 2; ++s) {
      const int row = (s * 4 + wave) * 16 + lrow;
      const uint32_t loff = (uint32_t)(s * 4 + wave) * 1024;
      char* lp = (char*)smem + loff;
      load_lds16(Ab + (long)(i0 + row) * C + kk + lk8, lp);
      load_lds16(Tb + (long)(n0 + row) * C + kk + lk8, lp + 8192);
    }
    __syncthreads();
    bf16x8 a[4], bb[4];
    for (int i = 0; i < 4; ++i)
      a[i]  = *(const bf16x8*)(smem +        (wr * 64 + i * 16 + m16) * 32 + q4 * 8);
    for (int j = 0; j < 4; ++j)
      bb[j] = *(const bf16x8*)(smem + 4096 + (wc * 64 + j * 16 + m16) * 32 + q4 * 8);
    for (int i = 0; i < 4; ++i)
      for (int j = 0; j < 4; ++j)
        acc[i][j] = __builtin_amdgcn_mfma_f32_16x16x32_bf16(a[i], bb[j], acc[i][j], 0, 0, 0);
    __syncthreads();
  }
  const float g = gamma[0];
  const float* xb = x   + (long)b * C * N;
  float*       ob = out + (long)b * C * N;
  for (int i = 0; i < 4; ++i) {
    const int rb = i0 + wr * 64 + i * 16 + q4 * 4;
    for (int j = 0; j < 4; ++j) {
      const int cc = n0 + wc * 64 + j * 16 + m16;
      for (int r = 0; r < 4; ++r) {
        const long idx = (long)(rb + r) * N + cc;
        ob[idx] = g * acc[i][j][r] + xb[idx];
      }
    }
  }
}

extern "C" void kernel_launch(void* const* d_in, const int* in_sizes, int n_in,
                              void* d_out, int out_size, void* d_ws, size_t ws_size,
                              hipStream_t stream) {
  const float* x     = (const float*)d_in[0];
  const float* gamma = (const float*)d_in[1];
  float* out = (float*)d_out;
  char*  ws  = (char*)d_ws;
  // ws layout: qT 64MB | E partials 4x16.78MB | attn 8.4MB  (~140 MB total)
  uint16_t* qT   = (uint16_t*)ws;
  float*    E    = (float*)  (ws + XSZ * 2);
  uint16_t* attn = (uint16_t*)(ws + XSZ * 2 + (long)ZSPLIT * ESZ * 4);

  cam_splitT <<<dim3(N / 64, C / 64, BB), 256, 0, stream>>>(x, qT);
  // 10 triangle tiles x 16 batches x 4 k-splits = 640 blocks (R2 bug: 256)
  cam_energy <<<dim3(640),                256, 0, stream>>>(x, E);
  cam_softmax<<<dim3((BB * C) / 4),       256, 0, stream>>>(E, attn);
  cam_pv     <<<dim3(N / 128, C / 128, BB), 256, 0, stream>>>(attn, qT, x, gamma, out);
}

// Round 4
// 414.745 us; speedup vs baseline: 1.3301x; 1.0851x over previous
//
#include <hip/hip_runtime.h>
#include <hip/hip_bf16.h>
#include <cstdint>

// CAM (DANet channel attention): out = gamma * softmax(rowmax(E)-E) @ q + x,
// E = q q^T per batch, q = x reshaped [B, C, N], B=16 C=512 N=4096.
//
// R4: energy gets a register-prefetch pipeline (next k-tile's global loads
// issued between barriers -> in flight during MFMA; VGPR loads are NOT
// drained by s_barrier, unlike global_load_lds) and ZSPLIT=8 (1280 blocks,
// 5 blocks/CU). PV moves to BK=64 (8 iters, 2x loads in flight). splitT
// vectorizes its LDS writes.

typedef short    bf16x8 __attribute__((ext_vector_type(8)));
typedef float    f32x4  __attribute__((ext_vector_type(4)));
typedef uint16_t u16x4  __attribute__((ext_vector_type(4)));
typedef uint16_t u16x8  __attribute__((ext_vector_type(8)));

#define AS1 __attribute__((address_space(1)))
#define AS3 __attribute__((address_space(3)))

__device__ __forceinline__ void load_lds16(const void* g, void* l) {
  __builtin_amdgcn_global_load_lds((const AS1 unsigned int*)g,
                                   (AS3 unsigned int*)l, 16, 0, 0);
}

static constexpr int  BB  = 16, C = 512, N = 4096;
static constexpr long XSZ = (long)BB * C * N;   // 33,554,432 elems
static constexpr long ESZ = (long)BB * C * C;   //  4,194,304 elems
static constexpr int  ZSPLIT = 8;

// ---------------- 1. transpose hi(RNE) for PV: qT[b][n][c] ------------------
__global__ __launch_bounds__(256) void cam_splitT(
    const float* __restrict__ x, uint16_t* __restrict__ qT) {
  __shared__ uint16_t tile[64][68];  // 136B row stride: 8B-aligned rows
  const int t  = threadIdx.x;
  const int b  = blockIdx.z;
  const int c0 = blockIdx.y * 64;
  const int n0 = blockIdx.x * 64;
  const float* xb  = x  + (long)b * C * N;
  uint16_t*    qTb = qT + (long)b * N * C;
  const int cl = t >> 4;
  const int nl = (t & 15) * 4;
  for (int r = 0; r < 4; ++r) {
    const int  c   = cl + r * 16;
    const long off = (long)(c0 + c) * N + n0 + nl;
    const float4 v = *(const float4*)(xb + off);
    const float vv[4] = {v.x, v.y, v.z, v.w};
    u16x4 hv;
    for (int k = 0; k < 4; ++k) {
      __hip_bfloat16 hb = __float2bfloat16(vv[k]);  // RNE for PV precision
      hv[k] = *(uint16_t*)&hb;
    }
    *(u16x4*)&tile[c][nl] = hv;  // one ds_write_b64
  }
  __syncthreads();
  for (int r = 0; r < 4; ++r) {
    const int n  = cl + r * 16;
    const int cc = (t & 15) * 4;
    u16x4 o = {tile[cc + 0][n], tile[cc + 1][n], tile[cc + 2][n], tile[cc + 3][n]};
    *(u16x4*)(qTb + (long)(n0 + n) * C + c0 + cc) = o;
  }
}

// RTZ split of 4 fp32 into packed bf16 hi (2 u32) + compensation lo (2 u32).
__device__ __forceinline__ void split4(float4 v, uint2& h, uint2& l) {
  const uint32_t u0 = __float_as_uint(v.x), u1 = __float_as_uint(v.y);
  const uint32_t u2 = __float_as_uint(v.z), u3 = __float_as_uint(v.w);
  const float r0 = v.x - __uint_as_float(u0 & 0xffff0000u);
  const float r1 = v.y - __uint_as_float(u1 & 0xffff0000u);
  const float r2 = v.z - __uint_as_float(u2 & 0xffff0000u);
  const float r3 = v.w - __uint_as_float(u3 & 0xffff0000u);
  h.x = (u0 >> 16) | (u1 & 0xffff0000u);
  h.y = (u2 >> 16) | (u3 & 0xffff0000u);
  l.x = (__float_as_uint(r0) >> 16) | (__float_as_uint(r1) & 0xffff0000u);
  l.y = (__float_as_uint(r2) >> 16) | (__float_as_uint(r3) & 0xffff0000u);
}

// -- 2. energy = HH^T + HL^T + LH^T, triangle tiles, split-K=8, reg prefetch -
__global__ __launch_bounds__(256) void cam_energy(
    const float* __restrict__ x, float* __restrict__ E) {
  __shared__ uint16_t smem[4 * 128 * 32];  // Ahi | Alo | Bhi | Blo, 32 KB
  const int tid = threadIdx.x;
  const int wave = tid >> 6, lane = tid & 63;
  // XCD swizzle: 10 blocks of one (b,z) group share blockIdx % 8.
  const int idx = blockIdx.x;              // 0..1279
  const int low = idx & 7, chunk = idx >> 3;       // chunk 0..159
  const int gh = chunk / 10, t = chunk - gh * 10;  // gh 0..15, t 0..9
  const int g  = gh * 8 + low;             // 0..127 group = (b, z)
  const int b  = g >> 3, z = g & 7;
  const int ti = (t < 4) ? 0 : (t < 7) ? 1 : (t < 9) ? 2 : 3;
  const int tj = t - ((ti * (9 - ti)) >> 1) + ti;
  const bool diag = (ti == tj);
  const int i0 = ti * 128, j0 = tj * 128;
  const float* xb = x + (long)b * C * N;
  const int sr = tid >> 3;                 // staging row 0..31 (per pass)
  const int sc = (tid & 7) * 4;            // staging k-offset (floats)
  const float* pA = xb + (long)(i0 + sr) * N + sc;
  const float* pB = xb + (long)(j0 + sr) * N + sc;
  uint16_t* smAh = smem;
  uint16_t* smAl = smem + 4096;
  uint16_t* smBh = diag ? smem        : smem + 8192;
  uint16_t* smBl = diag ? smem + 4096 : smem + 12288;
  const int wr = wave >> 1, wc = wave & 1;
  const int m16 = lane & 15, q4 = lane >> 4;
  f32x4 acc[4][4] = {};
  const int k0 = z * (N / ZSPLIT), kend = k0 + N / ZSPLIT;  // 512-wide chunk
  float4 ra[4], rb[4];
  #pragma unroll
  for (int p = 0; p < 4; ++p) {
    ra[p] = *(const float4*)(pA + k0 + (long)p * 32 * N);
    if (!diag) rb[p] = *(const float4*)(pB + k0 + (long)p * 32 * N);
  }
  for (int kk = k0; kk < kend; kk += 32) {
    #pragma unroll
    for (int p = 0; p < 4; ++p) {
      const int row = p * 32 + sr;
      uint2 h, l;
      split4(ra[p], h, l);
      *(uint2*)(smAh + row * 32 + sc) = h;
      *(uint2*)(smAl + row * 32 + sc) = l;
      if (!diag) {
        split4(rb[p], h, l);
        *(uint2*)(smem + 8192 + row * 32 + sc) = h;
        *(uint2*)(smem + 12288 + row * 32 + sc) = l;
      }
    }
    __syncthreads();
    // prefetch next k-tile: VGPR loads stay in flight through the MFMAs
    const int kn = (kk + 32 < kend) ? kk + 32 : k0;  // clamp (values unused)
    #pragma unroll
    for (int p = 0; p < 4; ++p) {
      ra[p] = *(const float4*)(pA + kn + (long)p * 32 * N);
      if (!diag) rb[p] = *(const float4*)(pB + kn + (long)p * 32 * N);
    }
    bf16x8 ah[4], al[4], bh[4], bl[4];
    for (int i = 0; i < 4; ++i) {
      const int r = wr * 64 + i * 16 + m16;
      ah[i] = *(const bf16x8*)(smAh + r * 32 + q4 * 8);
      al[i] = *(const bf16x8*)(smAl + r * 32 + q4 * 8);
    }
    for (int j = 0; j < 4; ++j) {
      const int r = wc * 64 + j * 16 + m16;
      bh[j] = *(const bf16x8*)(smBh + r * 32 + q4 * 8);
      bl[j] = *(const bf16x8*)(smBl + r * 32 + q4 * 8);
    }
    for (int i = 0; i < 4; ++i)
      for (int j = 0; j < 4; ++j) {
        acc[i][j] = __builtin_amdgcn_mfma_f32_16x16x32_bf16(ah[i], bh[j], acc[i][j], 0, 0, 0);
        acc[i][j] = __builtin_amdgcn_mfma_f32_16x16x32_bf16(ah[i], bl[j], acc[i][j], 0, 0, 0);
        acc[i][j] = __builtin_amdgcn_mfma_f32_16x16x32_bf16(al[i], bh[j], acc[i][j], 0, 0, 0);
      }
    __syncthreads();
  }
  float* Eb = E + (long)z * ESZ + (long)b * C * C;
  for (int i = 0; i < 4; ++i) {
    const int rb_ = i0 + wr * 64 + i * 16 + q4 * 4;
    for (int j = 0; j < 4; ++j) {
      const int cc = j0 + wc * 64 + j * 16 + m16;
      for (int r = 0; r < 4; ++r)
        Eb[(long)(rb_ + r) * C + cc] = acc[i][j][r];
      if (!diag)  // mirror: E[cc][rb..rb+3] = acc[0..3], contiguous float4
        *(f32x4*)(Eb + (long)cc * C + rb_) = acc[i][j];
    }
  }
}

// ---------------- 3. softmax(max-E) == exp(rowmin-E)/sum, -> bf16 ----------
__global__ __launch_bounds__(256) void cam_softmax(
    const float* __restrict__ E, uint16_t* __restrict__ attn) {
  const int t = threadIdx.x;
  const int wave = t >> 6, lane = t & 63;
  const long row = (long)blockIdx.x * 4 + wave;   // 0..8191
  const float* e = E + row * C + lane * 8;
  float vv[8] = {};
  for (int z = 0; z < ZSPLIT; ++z) {
    const float4 a0 = *(const float4*)(e + (long)z * ESZ);
    const float4 a1 = *(const float4*)(e + (long)z * ESZ + 4);
    vv[0] += a0.x; vv[1] += a0.y; vv[2] += a0.z; vv[3] += a0.w;
    vv[4] += a1.x; vv[5] += a1.y; vv[6] += a1.z; vv[7] += a1.w;
  }
  float m = vv[0];
  for (int k = 1; k < 8; ++k) m = fminf(m, vv[k]);
  for (int s = 32; s; s >>= 1) m = fminf(m, __shfl_xor(m, s));
  float w[8], sum = 0.f;
  for (int k = 0; k < 8; ++k) { w[k] = __expf(m - vv[k]); sum += w[k]; }
  for (int s = 32; s; s >>= 1) sum += __shfl_xor(sum, s);
  const float inv = 1.0f / sum;
  u16x8 o;
  for (int k = 0; k < 8; ++k) {
    __hip_bfloat16 h = __float2bfloat16(w[k] * inv);
    o[k] = *(uint16_t*)&h;
  }
  *(u16x8*)(attn + row * C + lane * 8) = o;
}

// ---------------- 4. out = gamma * (attn @ q) + x, BK=64 --------------------
__global__ __launch_bounds__(256) void cam_pv(
    const uint16_t* __restrict__ attn, const uint16_t* __restrict__ qT,
    const float* __restrict__ x, const float* __restrict__ gamma,
    float* __restrict__ out) {
  __shared__ uint16_t smem[2 * 128 * 64];  // A-tile | B-tile, 32 KB
  const int t = threadIdx.x;
  const int wave = t >> 6, lane = t & 63;
  const int b  = blockIdx.z;
  const int i0 = blockIdx.y * 128;
  const int n0 = blockIdx.x * 128;
  const uint16_t* Ab = attn + (long)b * C * C;
  const uint16_t* Tb = qT   + (long)b * N * C;
  const int lrow8 = lane >> 3;          // 8 lanes per 128B row
  const int lk8   = (lane & 7) * 8;     // bf16 col offset
  const int wr = wave >> 1, wc = wave & 1;
  const int m16 = lane & 15, q4 = lane >> 4;
  f32x4 acc[4][4] = {};
  for (int kk = 0; kk < C; kk += 64) {
    for (int s = 0; s < 4; ++s) {
      const int row = (s * 4 + wave) * 8 + lrow8;
      const uint32_t loff = (uint32_t)(s * 4 + wave) * 1024;
      char* lp = (char*)smem + loff;
      load_lds16(Ab + (long)(i0 + row) * C + kk + lk8, lp);
      load_lds16(Tb + (long)(n0 + row) * C + kk + lk8, lp + 16384);
    }
    __syncthreads();
    for (int h = 0; h < 2; ++h) {       // two k-halves of the BK=64 tile
      bf16x8 a[4], bb[4];
      for (int i = 0; i < 4; ++i)
        a[i]  = *(const bf16x8*)(smem +        (wr * 64 + i * 16 + m16) * 64 + h * 32 + q4 * 8);
      for (int j = 0; j < 4; ++j)
        bb[j] = *(const bf16x8*)(smem + 8192 + (wc * 64 + j * 16 + m16) * 64 + h * 32 + q4 * 8);
      for (int i = 0; i < 4; ++i)
        for (int j = 0; j < 4; ++j)
          acc[i][j] = __builtin_amdgcn_mfma_f32_16x16x32_bf16(a[i], bb[j], acc[i][j], 0, 0, 0);
    }
    __syncthreads();
  }
  const float g = gamma[0];
  const float* xb = x   + (long)b * C * N;
  float*       ob = out + (long)b * C * N;
  for (int i = 0; i < 4; ++i) {
    const int rb = i0 + wr * 64 + i * 16 + q4 * 4;
    for (int j = 0; j < 4; ++j) {
      const int cc = n0 + wc * 64 + j * 16 + m16;
      for (int r = 0; r < 4; ++r) {
        const long idx = (long)(rb + r) * N + cc;
        ob[idx] = g * acc[i][j][r] + xb[idx];
      }
    }
  }
}

extern "C" void kernel_launch(void* const* d_in, const int* in_sizes, int n_in,
                              void* d_out, int out_size, void* d_ws, size_t ws_size,
                              hipStream_t stream) {
  const float* x     = (const float*)d_in[0];
  const float* gamma = (const float*)d_in[1];
  float* out = (float*)d_out;
  char*  ws  = (char*)d_ws;
  // ws layout: qT 67MB | E partials 8x16.78MB=134MB | attn 8.4MB  (~210 MB)
  uint16_t* qT   = (uint16_t*)ws;
  float*    E    = (float*)  (ws + XSZ * 2);
  uint16_t* attn = (uint16_t*)(ws + XSZ * 2 + (long)ZSPLIT * ESZ * 4);

  cam_splitT <<<dim3(N / 64, C / 64, BB), 256, 0, stream>>>(x, qT);
  // 10 triangle tiles x 16 batches x 8 k-splits = 1280 blocks
  cam_energy <<<dim3(1280),               256, 0, stream>>>(x, E);
  cam_softmax<<<dim3((BB * C) / 4),       256, 0, stream>>>(E, attn);
  cam_pv     <<<dim3(N / 128, C / 128, BB), 256, 0, stream>>>(attn, qT, x, gamma, out);
}